// Round 1
// baseline (1735.373 us; speedup 1.0000x reference)
//
#include <hip/hip_runtime.h>

typedef _Float16 f16x8 __attribute__((ext_vector_type(8)));
typedef float    f32x4 __attribute__((ext_vector_type(4)));

#define GLDS16(gp, lp) \
  __builtin_amdgcn_global_load_lds((const __attribute__((address_space(1))) void*)(gp), \
                                   (__attribute__((address_space(3))) void*)(lp), 16, 0, 0)

// Problem constants: B=16, L=2048, Lp=2050, Din0=512, O=512, 3O=1536
#define NB   16
#define LL   2048
#define LP   2050
#define C3   1536
#define OO   512

// ---------------- x -> fp16 padded [B][LP][512] ----------------
__global__ void cvt_x_kernel(const float* __restrict__ x, _Float16* __restrict__ xp) {
  int t = blockIdx.x * blockDim.x + threadIdx.x;
  const int total = NB * LP * (512 / 8);
  if (t >= total) return;
  int c8  = (t & 63) << 3;
  int row = t >> 6;                 // padded row index b*LP + lp
  int b   = row / LP;
  int lp  = row - b * LP;
  f16x8 v;
  if (lp == 0 || lp == LP - 1) {
#pragma unroll
    for (int i = 0; i < 8; ++i) v[i] = (_Float16)0.f;
  } else {
    const float* s = x + ((size_t)(b * LL + lp - 1) * 512 + c8);
    const float4* s4 = (const float4*)s;
    float4 a = s4[0], bq = s4[1];
    v[0] = (_Float16)a.x;  v[1] = (_Float16)a.y;
    v[2] = (_Float16)a.z;  v[3] = (_Float16)a.w;
    v[4] = (_Float16)bq.x; v[5] = (_Float16)bq.y;
    v[6] = (_Float16)bq.z; v[7] = (_Float16)bq.w;
  }
  *(f16x8*)(xp + (size_t)row * 512 + c8) = v;
}

// ---------------- w [c][i][k] fp32 -> wt [c][k][i] fp16 ----------------
__global__ void cvt_w_kernel(const float* __restrict__ w, _Float16* __restrict__ wt,
                             int Din, int dinsh) {
  int t = blockIdx.x * blockDim.x + threadIdx.x;
  if (t >= C3 * Din) return;
  int c = t >> dinsh;
  int i = t & (Din - 1);
  const float* s = w + (size_t)t * 3;   // (c*Din + i)*3
  wt[((size_t)c * 3 + 0) * Din + i] = (_Float16)s[0];
  wt[((size_t)c * 3 + 1) * Din + i] = (_Float16)s[1];
  wt[((size_t)c * 3 + 2) * Din + i] = (_Float16)s[2];
}

// ---------------- zero pad rows of layer-1 input ----------------
__global__ void zero_pad_kernel(_Float16* __restrict__ xp1) {
  int t = blockIdx.x * blockDim.x + threadIdx.x;
  if (t >= NB * 2 * 1024) return;
  int col = t & 1023;
  int r   = (t >> 10) & 1;
  int b   = t >> 11;
  xp1[((size_t)b * LP + (r ? (LP - 1) : 0)) * 1024 + col] = (_Float16)0.f;
}

// ---------------- conv-as-GEMM: 128x128 tile, 3 taps, fp16 MFMA ----------------
// A: xpad [NB][LP][Din] fp16 ; W: [C3][3][Din] fp16 ; G: [NB][LL][C3] fp16 (activated)
__global__ __launch_bounds__(256) void conv_gemm(
    const _Float16* __restrict__ A, const _Float16* __restrict__ W,
    const float* __restrict__ bias, _Float16* __restrict__ G, int Din)
{
  const int nT = blockIdx.x, lT = blockIdx.y, b = blockIdx.z;
  const int tid  = (int)threadIdx.x;
  const int w    = tid >> 6, lane = tid & 63;
  const int wr   = w >> 1,   wc   = w & 1;
  const int l0   = lT << 7,  n0   = nT << 7;

  __shared__ _Float16 Als[128 * 32];
  __shared__ _Float16 Bls[128 * 32];

  f32x4 acc[4][4];
  const f32x4 zed = {0.f, 0.f, 0.f, 0.f};
#pragma unroll
  for (int i = 0; i < 4; ++i)
#pragma unroll
    for (int j = 0; j < 4; ++j) acc[i][j] = zed;

  const int mloc0 = (w << 4) + (lane >> 2);  // chunk row for issue j=0
  const int ke    = (lane & 3) << 3;         // k element offset 0/8/16/24

  for (int tap = 0; tap < 3; ++tap) {
    const _Float16* Ab = A + ((size_t)(b * LP + l0 + tap)) * Din;
    for (int kt = 0; kt < Din; kt += 32) {
      __syncthreads();
#pragma unroll
      for (int j = 0; j < 2; ++j) {
        const int m     = mloc0 + (j << 6);
        const int chunk = (j << 2) + w;      // wave-uniform LDS chunk
        GLDS16(Ab + (size_t)m * Din + (kt + ke), (char*)Als + (chunk << 10));
        GLDS16(W + ((size_t)((n0 + m) * 3 + tap)) * Din + (kt + ke),
               (char*)Bls + (chunk << 10));
      }
      __syncthreads();   // compiler drains vmcnt(0) before barrier
      f16x8 af[4], bf[4];
      const int rA = lane & 15;
      const int kc = (lane >> 4) << 4;       // byte offset of 8-elem k-chunk
#pragma unroll
      for (int i = 0; i < 4; ++i) {
        af[i] = *(const f16x8*)((const char*)Als + ((wr * 64 + i * 16 + rA) << 6) + kc);
        bf[i] = *(const f16x8*)((const char*)Bls + ((wc * 64 + i * 16 + rA) << 6) + kc);
      }
#pragma unroll
      for (int mi = 0; mi < 4; ++mi)
#pragma unroll
        for (int ni = 0; ni < 4; ++ni)
          acc[mi][ni] = __builtin_amdgcn_mfma_f32_16x16x32_f16(af[mi], bf[ni], acc[mi][ni], 0, 0, 0);
    }
  }

  // epilogue: bias + sigmoid/sigmoid/tanh, write fp16 gates
#pragma unroll
  for (int ni = 0; ni < 4; ++ni) {
    const int col = n0 + wc * 64 + ni * 16 + (lane & 15);
    const float bv = bias[col];
#pragma unroll
    for (int mi = 0; mi < 4; ++mi) {
#pragma unroll
      for (int r = 0; r < 4; ++r) {
        const int l = l0 + wr * 64 + mi * 16 + ((lane >> 4) << 2) + r;
        float v = acc[mi][ni][r] + bv;
        v = fminf(fmaxf(v, -30.f), 30.f);
        float a;
        if (col < 1024) {                 // f and o gates: sigmoid
          a = 1.f / (1.f + __expf(-v));
        } else {                          // z gate: tanh
          float e = __expf(2.f * v);
          a = (e - 1.f) / (e + 1.f);
        }
        G[((size_t)(b * LL + l)) * C3 + col] = (_Float16)a;
      }
    }
  }
}

// ---------------- fo_pool, 3-phase chunked scan (32 chunks x 64 steps) ----------------
__global__ void fo_phase1(const _Float16* __restrict__ g, float* __restrict__ P,
                          float* __restrict__ S, int dir) {
  int t = blockIdx.x * blockDim.x + threadIdx.x;
  if (t >= 32 * 8192) return;
  int bo = t & 8191;
  int ch = t >> 13;
  int b = bo >> 9, o = bo & 511;
  float c = 0.f, p = 1.f;
  const int s0 = ch * 64;
  for (int k = 0; k < 64; ++k) {
    int s = s0 + k;
    int l = dir ? (2047 - s) : s;
    size_t base = ((size_t)(b * LL + l)) * C3 + o;
    float f = (float)g[base];
    float z = (float)g[base + 1024];
    c = f * c + (1.f - f) * z;
    p *= f;
  }
  P[t] = p;
  S[t] = c;
}

__global__ void fo_phase2(const float* __restrict__ P, const float* __restrict__ S,
                          float* __restrict__ cst) {
  int bo = blockIdx.x * blockDim.x + threadIdx.x;
  if (bo >= 8192) return;
  float c = 0.f;
#pragma unroll
  for (int j = 0; j < 32; ++j) {
    cst[j * 8192 + bo] = c;
    c = P[j * 8192 + bo] * c + S[j * 8192 + bo];
  }
}

__global__ void fo_phase3(const _Float16* __restrict__ g, const float* __restrict__ cst,
                          int dir, int layer, _Float16* __restrict__ nxt,
                          float* __restrict__ out2, float* __restrict__ hc) {
  int t = blockIdx.x * blockDim.x + threadIdx.x;
  if (t >= 32 * 8192) return;
  int bo = t & 8191;
  int ch = t >> 13;
  int b = bo >> 9, o = bo & 511;
  float c = cst[t];
  const int s0 = ch * 64;
  for (int k = 0; k < 64; ++k) {
    int s = s0 + k;
    int l = dir ? (2047 - s) : s;
    size_t base = ((size_t)(b * LL + l)) * C3 + o;
    float f  = (float)g[base];
    float og = (float)g[base + 512];
    float z  = (float)g[base + 1024];
    c = f * c + (1.f - f) * z;
    float h = c * og;
    if (layer == 0)
      nxt[((size_t)(b * LP + l + 1)) * 1024 + dir * 512 + o] = (_Float16)h;
    else
      out2[((size_t)(b * LL + l)) * 1024 + dir * 512 + o] = h;
    if (l == 2047) {                      // last_h / last_c slices
      hc[(layer * 16 + b) * 1024 + dir * 512 + o] = h;
      hc[32768 + (layer * 16 + b) * 1024 + dir * 512 + o] = c;
    }
  }
}

// ---------------- launch ----------------
extern "C" void kernel_launch(void* const* d_in, const int* in_sizes, int n_in,
                              void* d_out, int out_size, void* d_ws, size_t ws_size,
                              hipStream_t stream) {
  const float* x   = (const float*)d_in[0];
  const float* w0f = (const float*)d_in[1];
  const float* b0f = (const float*)d_in[2];
  const float* w0r = (const float*)d_in[3];
  const float* b0r = (const float*)d_in[4];
  const float* w1f = (const float*)d_in[5];
  const float* b1f = (const float*)d_in[6];
  const float* w1r = (const float*)d_in[7];
  const float* b1r = (const float*)d_in[8];
  float* out = (float*)d_out;

  char* ws = (char*)d_ws;
  // workspace layout (bytes)
  _Float16* xp0  = (_Float16*)(ws + 0);           // 16*2050*512*2  = 33,587,200
  _Float16* xp1  = (_Float16*)(ws + 33587200);    // 16*2050*1024*2 = 67,174,400
  _Float16* wt0f = (_Float16*)(ws + 100761600);   // 4,718,592
  _Float16* wt0r = (_Float16*)(ws + 105480192);   // 4,718,592
  _Float16* wt1f = (_Float16*)(ws + 110198784);   // 9,437,184
  _Float16* wt1r = (_Float16*)(ws + 119635968);   // 9,437,184
  _Float16* g    = (_Float16*)(ws + 129073152);   // 16*2048*1536*2 = 100,663,296
  float*    P    = (float*)(ws + 229736448);      // 1,048,576
  float*    S    = (float*)(ws + 230785024);      // 1,048,576
  float*    cst  = (float*)(ws + 231833600);      // 1,048,576

  float* hc = out + (size_t)16 * 2048 * 1024;     // hidden @ +0, cell @ +32768

  cvt_x_kernel<<<8200, 256, 0, stream>>>(x, xp0);
  cvt_w_kernel<<<3072, 256, 0, stream>>>(w0f, wt0f, 512, 9);
  cvt_w_kernel<<<3072, 256, 0, stream>>>(w0r, wt0r, 512, 9);
  cvt_w_kernel<<<6144, 256, 0, stream>>>(w1f, wt1f, 1024, 10);
  cvt_w_kernel<<<6144, 256, 0, stream>>>(w1r, wt1r, 1024, 10);
  zero_pad_kernel<<<128, 256, 0, stream>>>(xp1);

  dim3 gg(12, 16, 16);

  // layer 0, forward
  conv_gemm<<<gg, 256, 0, stream>>>(xp0, wt0f, b0f, g, 512);
  fo_phase1<<<1024, 256, 0, stream>>>(g, P, S, 0);
  fo_phase2<<<32, 256, 0, stream>>>(P, S, cst);
  fo_phase3<<<1024, 256, 0, stream>>>(g, cst, 0, 0, xp1, out, hc);
  // layer 0, reverse
  conv_gemm<<<gg, 256, 0, stream>>>(xp0, wt0r, b0r, g, 512);
  fo_phase1<<<1024, 256, 0, stream>>>(g, P, S, 1);
  fo_phase2<<<32, 256, 0, stream>>>(P, S, cst);
  fo_phase3<<<1024, 256, 0, stream>>>(g, cst, 1, 0, xp1, out, hc);
  // layer 1, forward
  conv_gemm<<<gg, 256, 0, stream>>>(xp1, wt1f, b1f, g, 1024);
  fo_phase1<<<1024, 256, 0, stream>>>(g, P, S, 0);
  fo_phase2<<<32, 256, 0, stream>>>(P, S, cst);
  fo_phase3<<<1024, 256, 0, stream>>>(g, cst, 0, 1, xp1, out, hc);
  // layer 1, reverse
  conv_gemm<<<gg, 256, 0, stream>>>(xp1, wt1r, b1r, g, 1024);
  fo_phase1<<<1024, 256, 0, stream>>>(g, P, S, 1);
  fo_phase2<<<32, 256, 0, stream>>>(P, S, cst);
  fo_phase3<<<1024, 256, 0, stream>>>(g, cst, 1, 1, xp1, out, hc);
}

// Round 2
// 1426.200 us; speedup vs baseline: 1.2168x; 1.2168x over previous
//
#include <hip/hip_runtime.h>

typedef _Float16 f16x8 __attribute__((ext_vector_type(8)));
typedef float    f32x4 __attribute__((ext_vector_type(4)));

#define GLDS16(gp, lp) \
  __builtin_amdgcn_global_load_lds((const __attribute__((address_space(1))) void*)(gp), \
                                   (__attribute__((address_space(3))) void*)(lp), 16, 0, 0)

// Problem constants: B=16, L=2048, Lp=2050, Din0=512, O=512, 3O=1536
#define NB   16
#define LL   2048
#define LP   2050
#define C3   1536
#define OO   512

// ---------------- x -> fp16 padded [B][LP][512] ----------------
__global__ void cvt_x_kernel(const float* __restrict__ x, _Float16* __restrict__ xp) {
  int t = blockIdx.x * blockDim.x + threadIdx.x;
  const int total = NB * LP * (512 / 8);
  if (t >= total) return;
  int c8  = (t & 63) << 3;
  int row = t >> 6;                 // padded row index b*LP + lp
  int b   = row / LP;
  int lp  = row - b * LP;
  f16x8 v;
  if (lp == 0 || lp == LP - 1) {
#pragma unroll
    for (int i = 0; i < 8; ++i) v[i] = (_Float16)0.f;
  } else {
    const float* s = x + ((size_t)(b * LL + lp - 1) * 512 + c8);
    const float4* s4 = (const float4*)s;
    float4 a = s4[0], bq = s4[1];
    v[0] = (_Float16)a.x;  v[1] = (_Float16)a.y;
    v[2] = (_Float16)a.z;  v[3] = (_Float16)a.w;
    v[4] = (_Float16)bq.x; v[5] = (_Float16)bq.y;
    v[6] = (_Float16)bq.z; v[7] = (_Float16)bq.w;
  }
  *(f16x8*)(xp + (size_t)row * 512 + c8) = v;
}

// ---------------- w [c][i][k] fp32 -> wt [c][k][i] fp16 ----------------
__global__ void cvt_w_kernel(const float* __restrict__ w, _Float16* __restrict__ wt,
                             int Din, int dinsh) {
  int t = blockIdx.x * blockDim.x + threadIdx.x;
  if (t >= C3 * Din) return;
  int c = t >> dinsh;
  int i = t & (Din - 1);
  const float* s = w + (size_t)t * 3;   // (c*Din + i)*3
  wt[((size_t)c * 3 + 0) * Din + i] = (_Float16)s[0];
  wt[((size_t)c * 3 + 1) * Din + i] = (_Float16)s[1];
  wt[((size_t)c * 3 + 2) * Din + i] = (_Float16)s[2];
}

// ---------------- zero pad rows of layer-1 input ----------------
__global__ void zero_pad_kernel(_Float16* __restrict__ xp1) {
  int t = blockIdx.x * blockDim.x + threadIdx.x;
  if (t >= NB * 2 * 1024) return;
  int col = t & 1023;
  int r   = (t >> 10) & 1;
  int b   = t >> 11;
  xp1[((size_t)b * LP + (r ? (LP - 1) : 0)) * 1024 + col] = (_Float16)0.f;
}

// ---------------- conv-as-GEMM: 128x128 tile, tap-fused, swizzled LDS ----------------
// A: xpad [NB][LP][Din] fp16 ; W: [C3][3][Din] fp16 ; G: [NB][LL][C3] fp16 (activated)
// LDS storage swizzle: within each 64B row r, 16B slot s holds k-chunk (s ^ (r&3)).
// Achieved by pre-swizzling the GLOBAL source k-offset (dest stays linear for
// global_load_lds) and XOR-ing the ds_read byte offset. 16-row column reads then
// hit 8 distinct bank-quads (2-way alias = free) instead of 8-way conflicts.
__global__ __launch_bounds__(256) void conv_gemm(
    const _Float16* __restrict__ A, const _Float16* __restrict__ W,
    const float* __restrict__ bias, _Float16* __restrict__ G, int Din)
{
  const int nT = blockIdx.x, lT = blockIdx.y, b = blockIdx.z;
  const int tid  = (int)threadIdx.x;
  const int w    = tid >> 6, lane = tid & 63;
  const int wr   = w >> 1,   wc   = w & 1;
  const int l0   = lT << 7,  n0   = nT << 7;

  __shared__ _Float16 Als[132 * 32];        // 130 rows staged (128 + 2 tap halo)
  __shared__ _Float16 Bls[3 * 128 * 32];    // 3 tap tiles

  f32x4 acc[4][4];
  const f32x4 zed = {0.f, 0.f, 0.f, 0.f};
#pragma unroll
  for (int i = 0; i < 4; ++i)
#pragma unroll
    for (int j = 0; j < 4; ++j) acc[i][j] = zed;

  const int rl   = lane >> 2;                              // row within 16-row chunk
  const int kswz = ((lane & 3) ^ (rl & 3)) << 3;           // swizzled k-elem offset
  const _Float16* Ab = A + ((size_t)(b * LP + l0)) * Din;

  const int rA = lane & 15;        // fragment row within 16
  const int kq = lane >> 4;        // k-chunk quarter 0..3

  for (int kt = 0; kt < Din; kt += 32) {
    __syncthreads();               // previous iteration's reads done
    // ---- stage A: rows 0..129 of [l0 .. l0+129] ----
#pragma unroll
    for (int j = 0; j < 2; ++j) {
      const int chunk = w + (j << 2);                      // wave-uniform
      const int row   = (chunk << 4) + rl;
      GLDS16(Ab + (size_t)row * Din + (kt + kswz), (char*)Als + (chunk << 10));
    }
    if (w == 0 && lane < 8) {                              // rows 128,129
      const int row = 128 + rl;
      GLDS16(Ab + (size_t)row * Din + (kt + kswz), (char*)Als + (8 << 10));
    }
    // ---- stage B: 3 taps x 128 rows = 24 chunks, 6 per wave ----
#pragma unroll
    for (int j = 0; j < 6; ++j) {
      const int chunkid = w * 6 + j;                       // wave-uniform
      const int tap     = chunkid >> 3;
      const int row     = ((chunkid & 7) << 4) + rl;       // row within tap tile
      GLDS16(W + ((size_t)((n0 + row) * 3 + tap)) * Din + (kt + kswz),
             (char*)Bls + (chunkid << 10));
    }
    __syncthreads();               // compiler drains vmcnt(0) before barrier

#pragma unroll
    for (int tap = 0; tap < 3; ++tap) {
      f16x8 af[4], bf[4];
#pragma unroll
      for (int i = 0; i < 4; ++i) {
        const int ra = wr * 64 + i * 16 + rA + tap;
        const int rb = wc * 64 + i * 16 + rA;
        af[i] = *(const f16x8*)((const char*)Als + (ra << 6) + ((kq ^ (ra & 3)) << 4));
        bf[i] = *(const f16x8*)((const char*)Bls + (tap << 13) + (rb << 6) + ((kq ^ (rb & 3)) << 4));
      }
#pragma unroll
      for (int mi = 0; mi < 4; ++mi)
#pragma unroll
        for (int ni = 0; ni < 4; ++ni)
          acc[mi][ni] = __builtin_amdgcn_mfma_f32_16x16x32_f16(af[mi], bf[ni], acc[mi][ni], 0, 0, 0);
    }
  }

  // epilogue: bias + sigmoid/sigmoid/tanh, write fp16 gates
#pragma unroll
  for (int ni = 0; ni < 4; ++ni) {
    const int col = n0 + wc * 64 + ni * 16 + (lane & 15);
    const float bv = bias[col];
#pragma unroll
    for (int mi = 0; mi < 4; ++mi) {
#pragma unroll
      for (int r = 0; r < 4; ++r) {
        const int l = l0 + wr * 64 + mi * 16 + ((lane >> 4) << 2) + r;
        float v = acc[mi][ni][r] + bv;
        v = fminf(fmaxf(v, -30.f), 30.f);
        float a;
        if (col < 1024) {                 // f and o gates: sigmoid
          a = 1.f / (1.f + __expf(-v));
        } else {                          // z gate: tanh
          float e = __expf(2.f * v);
          a = (e - 1.f) / (e + 1.f);
        }
        G[((size_t)(b * LL + l)) * C3 + col] = (_Float16)a;
      }
    }
  }
}

// ---------------- fo_pool, 3-phase chunked scan (32 chunks x 64 steps) ----------------
__global__ void fo_phase1(const _Float16* __restrict__ g, float* __restrict__ P,
                          float* __restrict__ S, int dir) {
  int t = blockIdx.x * blockDim.x + threadIdx.x;
  if (t >= 32 * 8192) return;
  int bo = t & 8191;
  int ch = t >> 13;
  int b = bo >> 9, o = bo & 511;
  float c = 0.f, p = 1.f;
  const int s0 = ch * 64;
  for (int k = 0; k < 64; ++k) {
    int s = s0 + k;
    int l = dir ? (2047 - s) : s;
    size_t base = ((size_t)(b * LL + l)) * C3 + o;
    float f = (float)g[base];
    float z = (float)g[base + 1024];
    c = f * c + (1.f - f) * z;
    p *= f;
  }
  P[t] = p;
  S[t] = c;
}

__global__ void fo_phase2(const float* __restrict__ P, const float* __restrict__ S,
                          float* __restrict__ cst) {
  int bo = blockIdx.x * blockDim.x + threadIdx.x;
  if (bo >= 8192) return;
  float c = 0.f;
#pragma unroll
  for (int j = 0; j < 32; ++j) {
    cst[j * 8192 + bo] = c;
    c = P[j * 8192 + bo] * c + S[j * 8192 + bo];
  }
}

__global__ void fo_phase3(const _Float16* __restrict__ g, const float* __restrict__ cst,
                          int dir, int layer, _Float16* __restrict__ nxt,
                          float* __restrict__ out2, float* __restrict__ hc) {
  int t = blockIdx.x * blockDim.x + threadIdx.x;
  if (t >= 32 * 8192) return;
  int bo = t & 8191;
  int ch = t >> 13;
  int b = bo >> 9, o = bo & 511;
  float c = cst[t];
  const int s0 = ch * 64;
  for (int k = 0; k < 64; ++k) {
    int s = s0 + k;
    int l = dir ? (2047 - s) : s;
    size_t base = ((size_t)(b * LL + l)) * C3 + o;
    float f  = (float)g[base];
    float og = (float)g[base + 512];
    float z  = (float)g[base + 1024];
    c = f * c + (1.f - f) * z;
    float h = c * og;
    if (layer == 0)
      nxt[((size_t)(b * LP + l + 1)) * 1024 + dir * 512 + o] = (_Float16)h;
    else
      out2[((size_t)(b * LL + l)) * 1024 + dir * 512 + o] = h;
    if (l == 2047) {                      // last_h / last_c slices
      hc[(layer * 16 + b) * 1024 + dir * 512 + o] = h;
      hc[32768 + (layer * 16 + b) * 1024 + dir * 512 + o] = c;
    }
  }
}

// ---------------- launch ----------------
extern "C" void kernel_launch(void* const* d_in, const int* in_sizes, int n_in,
                              void* d_out, int out_size, void* d_ws, size_t ws_size,
                              hipStream_t stream) {
  const float* x   = (const float*)d_in[0];
  const float* w0f = (const float*)d_in[1];
  const float* b0f = (const float*)d_in[2];
  const float* w0r = (const float*)d_in[3];
  const float* b0r = (const float*)d_in[4];
  const float* w1f = (const float*)d_in[5];
  const float* b1f = (const float*)d_in[6];
  const float* w1r = (const float*)d_in[7];
  const float* b1r = (const float*)d_in[8];
  float* out = (float*)d_out;

  char* ws = (char*)d_ws;
  // workspace layout (bytes)
  _Float16* xp0  = (_Float16*)(ws + 0);           // 16*2050*512*2  = 33,587,200
  _Float16* xp1  = (_Float16*)(ws + 33587200);    // 16*2050*1024*2 = 67,174,400
  _Float16* wt0f = (_Float16*)(ws + 100761600);   // 4,718,592
  _Float16* wt0r = (_Float16*)(ws + 105480192);   // 4,718,592
  _Float16* wt1f = (_Float16*)(ws + 110198784);   // 9,437,184
  _Float16* wt1r = (_Float16*)(ws + 119635968);   // 9,437,184
  _Float16* g    = (_Float16*)(ws + 129073152);   // 16*2048*1536*2 = 100,663,296
  float*    P    = (float*)(ws + 229736448);      // 1,048,576
  float*    S    = (float*)(ws + 230785024);      // 1,048,576
  float*    cst  = (float*)(ws + 231833600);      // 1,048,576

  float* hc = out + (size_t)16 * 2048 * 1024;     // hidden @ +0, cell @ +32768

  cvt_x_kernel<<<8200, 256, 0, stream>>>(x, xp0);
  cvt_w_kernel<<<3072, 256, 0, stream>>>(w0f, wt0f, 512, 9);
  cvt_w_kernel<<<3072, 256, 0, stream>>>(w0r, wt0r, 512, 9);
  cvt_w_kernel<<<6144, 256, 0, stream>>>(w1f, wt1f, 1024, 10);
  cvt_w_kernel<<<6144, 256, 0, stream>>>(w1r, wt1r, 1024, 10);
  zero_pad_kernel<<<128, 256, 0, stream>>>(xp1);

  dim3 gg(12, 16, 16);

  // layer 0, forward
  conv_gemm<<<gg, 256, 0, stream>>>(xp0, wt0f, b0f, g, 512);
  fo_phase1<<<1024, 256, 0, stream>>>(g, P, S, 0);
  fo_phase2<<<32, 256, 0, stream>>>(P, S, cst);
  fo_phase3<<<1024, 256, 0, stream>>>(g, cst, 0, 0, xp1, out, hc);
  // layer 0, reverse
  conv_gemm<<<gg, 256, 0, stream>>>(xp0, wt0r, b0r, g, 512);
  fo_phase1<<<1024, 256, 0, stream>>>(g, P, S, 1);
  fo_phase2<<<32, 256, 0, stream>>>(P, S, cst);
  fo_phase3<<<1024, 256, 0, stream>>>(g, cst, 1, 0, xp1, out, hc);
  // layer 1, forward
  conv_gemm<<<gg, 256, 0, stream>>>(xp1, wt1f, b1f, g, 1024);
  fo_phase1<<<1024, 256, 0, stream>>>(g, P, S, 0);
  fo_phase2<<<32, 256, 0, stream>>>(P, S, cst);
  fo_phase3<<<1024, 256, 0, stream>>>(g, cst, 0, 1, xp1, out, hc);
  // layer 1, reverse
  conv_gemm<<<gg, 256, 0, stream>>>(xp1, wt1r, b1r, g, 1024);
  fo_phase1<<<1024, 256, 0, stream>>>(g, P, S, 1);
  fo_phase2<<<32, 256, 0, stream>>>(P, S, cst);
  fo_phase3<<<1024, 256, 0, stream>>>(g, cst, 1, 1, xp1, out, hc);
}